// Round 2
// baseline (510.168 us; speedup 1.0000x reference)
//
#include <hip/hip_runtime.h>
#include <hip/hip_bf16.h>
#include <stdint.h>

#define B_    4
#define S_    2048
#define DIN   4096
#define DOUT  4096
#define NNZ_  167772
#define M_    (B_*S_)   // 8192

typedef __attribute__((ext_vector_type(4))) float f32x4;
typedef __attribute__((ext_vector_type(16))) float f32x16;
typedef __attribute__((ext_vector_type(8))) short s16x8;
typedef __attribute__((ext_vector_type(8))) unsigned short u16x8;

__device__ __forceinline__ unsigned short f2bf(float f) {
    unsigned int u = __float_as_uint(f);
    u += 0x7FFFu + ((u >> 16) & 1u);   // RNE; inputs finite, no NaN handling needed
    return (unsigned short)(u >> 16);
}

__device__ __forceinline__ void gload16(const void* g, void* l) {
    __builtin_amdgcn_global_load_lds(
        (const __attribute__((address_space(1))) unsigned int*)g,
        (__attribute__((address_space(3))) unsigned int*)l,
        16, 0, 0);
}

// ---- prep kernels (unchanged) ----

__global__ void zero_kernel(float* __restrict__ p, int n4) {
    int i = blockIdx.x * blockDim.x + threadIdx.x;
    if (i < n4) reinterpret_cast<f32x4*>(p)[i] = f32x4{0.f, 0.f, 0.f, 0.f};
}

__global__ void scatter_kernel(const float* __restrict__ vals,
                               const int* __restrict__ rows,
                               const int* __restrict__ cols,
                               float* __restrict__ delta, int nnz) {
    int i = blockIdx.x * blockDim.x + threadIdx.x;
    if (i < nnz) atomicAdd(delta + (size_t)rows[i] * DIN + cols[i], vals[i]);
}

__global__ void fuse_w_kernel(const float* __restrict__ W,
                              const float* __restrict__ delta,
                              unsigned short* __restrict__ Wb, int n8) {
    int i = blockIdx.x * blockDim.x + threadIdx.x;
    if (i >= n8) return;
    const f32x4* w4 = reinterpret_cast<const f32x4*>(W);
    const f32x4* d4 = reinterpret_cast<const f32x4*>(delta);
    f32x4 a0 = w4[2*i], a1 = w4[2*i+1];
    f32x4 b0 = d4[2*i], b1 = d4[2*i+1];
    u16x8 o;
    o[0]=f2bf(a0[0]+b0[0]); o[1]=f2bf(a0[1]+b0[1]); o[2]=f2bf(a0[2]+b0[2]); o[3]=f2bf(a0[3]+b0[3]);
    o[4]=f2bf(a1[0]+b1[0]); o[5]=f2bf(a1[1]+b1[1]); o[6]=f2bf(a1[2]+b1[2]); o[7]=f2bf(a1[3]+b1[3]);
    reinterpret_cast<u16x8*>(Wb)[i] = o;
}

__global__ void cvt_x_kernel(const float* __restrict__ x,
                             unsigned short* __restrict__ xb, int n8) {
    int i = blockIdx.x * blockDim.x + threadIdx.x;
    if (i >= n8) return;
    const f32x4* x4 = reinterpret_cast<const f32x4*>(x);
    f32x4 a0 = x4[2*i], a1 = x4[2*i+1];
    u16x8 o;
    o[0]=f2bf(a0[0]); o[1]=f2bf(a0[1]); o[2]=f2bf(a0[2]); o[3]=f2bf(a0[3]);
    o[4]=f2bf(a1[0]); o[5]=f2bf(a1[1]); o[6]=f2bf(a1[2]); o[7]=f2bf(a1[3]);
    reinterpret_cast<u16x8*>(xb)[i] = o;
}

// ---- GEMM: C[m][o] = sum_k xb[m][k] * Wb[o][k] + bias[o] ----
// 256x256 tile, BK=64, 8 waves (2Mx4N), 512 threads, 128 KiB dynamic LDS.
// Round 2 change: 16x16x32 -> 32x32x16 MFMA (2495 vs 2075 TF ubench rate,
// half the MFMA issue slots per phase). Per-wave output 128x64 = 4x2 frags
// of 32x32, 8 MFMA per phase, same 12/8/4/0 ds_read pattern, same
// XOR-swizzle (slot ^= row&7; staging pre-swizzles the GLOBAL source so
// global_load_lds dest stays linear), same counted vmcnt(4) boundaries,
// setprio around MFMA clusters, bijective XCD block swizzle.
//
// Staging schedule (race-free by construction):
//   during tile t (reads buf[p=t&1]):
//     ph1: stage (t+1).B.h0 -> buf[1-p]   (buffer not read this tile)
//     ph2: stage (t+1).B.h1 -> buf[1-p]
//     ph3: stage (t+2).A.h0 -> buf[p]     (A-region reads finished ph2)
//     ph4: stage (t+2).A.h1 -> buf[p]
//   boundary: s_waitcnt vmcnt(4)  -> (t+1) fully landed, (t+2).A in flight

__global__ __launch_bounds__(512, 2) void gemm_kernel(
    const unsigned short* __restrict__ A,   // xb [M][K] bf16 bits
    const unsigned short* __restrict__ Bw,  // Wb [N][K] bf16 bits
    const float* __restrict__ bias,
    float* __restrict__ C)                  // [M][N] fp32
{
    constexpr int K  = DIN;    // 4096
    constexpr int N  = DOUT;   // 4096
    constexpr int KB = K * 2;  // 8192 bytes per row
    extern __shared__ char smem[];   // [2 bufs][A 32K | B 32K] = 128 KiB

    const int tid  = threadIdx.x;
    const int wave = tid >> 6;
    const int lane = tid & 63;
    const int wr = wave >> 2;          // 0..1  (M waves)
    const int wc = wave & 3;           // 0..3  (N waves)
    const int l31 = lane & 31;
    const int hi  = lane >> 5;         // 0..1
    const int x7  = lane & 7;

    // XCD-aware bijective swizzle: 512 wgs, 8 XCDs -> 64 contiguous wgs/XCD.
    const int wg  = blockIdx.x;
    const int swz = (wg & 7) * 64 + (wg >> 3);
    const int bx  = swz & 15;          // N block 0..15
    const int by  = swz >> 4;          // M block 0..31
    const int rowBase = by * 256;
    const int colBase = bx * 256;

    // staging: per-thread global source, pre-swizzled (slot ^= row&7).
    // LDS dest stays linear: base + instr*8192 + wave*1024 (+ lane*16 impl.)
    const int r0    = tid >> 3;                   // row within 64-row chunk
    const int gslot = (tid & 7) ^ (r0 & 7);
    const char* gA = (const char*)A  + (size_t)(rowBase + r0) * KB + gslot * 16;
    const char* gB = (const char*)Bw + (size_t)(colBase + r0) * KB + gslot * 16;
    const int wvoff = wave * 1024;

    // LDS read bases. A row = wr*128 + mf*32 + l31, B row = wc*64 + nf*32 + l31.
    // slot(ks) = (ks*2 + hi) ^ x7  (row&7 == x7 since mf*32/nf*32 are mult of 8)
    int sA[4];
    #pragma unroll
    for (int ks = 0; ks < 4; ++ks) sA[ks] = ((ks * 2 + hi) ^ x7) * 16;
    const char* aB0 = smem +          (wr * 128 + l31) * 128;
    const char* aB1 = smem + 65536 +  (wr * 128 + l31) * 128;
    const char* bB0 = smem + 32768 +          (wc * 64 + l31) * 128;
    const char* bB1 = smem + 65536 + 32768 +  (wc * 64 + l31) * 128;

    f32x16 acc00{}, acc10{}, acc20{}, acc30{};   // [mf][nf=0]
    f32x16 acc01{}, acc11{}, acc21{}, acc31{};   // [mf][nf=1]

#define STAGE_A(P, T, H) do { \
    const char* g_ = gA + (size_t)(T) * 128 + (size_t)(H) * 1048576; \
    gload16(g_,          smem + (P) * 65536 + (H) * 16384 + wvoff); \
    gload16(g_ + 524288, smem + (P) * 65536 + (H) * 16384 + 8192 + wvoff); \
} while (0)

#define STAGE_B(P, T, H) do { \
    const char* g_ = gB + (size_t)(T) * 128 + (size_t)(H) * 1048576; \
    gload16(g_,          smem + (P) * 65536 + 32768 + (H) * 16384 + wvoff); \
    gload16(g_ + 524288, smem + (P) * 65536 + 32768 + (H) * 16384 + 8192 + wvoff); \
} while (0)

#define BAR() asm volatile("s_barrier" ::: "memory")

#define MFMA32(D, Af, Bf) D = __builtin_amdgcn_mfma_f32_32x32x16_bf16(Af, Bf, D, 0, 0, 0)

#define TILE(AB, BB, OP, T, SB, SA, VN) do { \
    s16x8 a01[2][4], a23[2][4], b0[4], b1[4]; \
    /* ---- phase 1: frags (m0,m1) x n0, all ks ---- */ \
    _Pragma("unroll") \
    for (int ks_ = 0; ks_ < 4; ++ks_) { \
        a01[0][ks_] = *(const s16x8*)(AB +        sA[ks_]); \
        a01[1][ks_] = *(const s16x8*)(AB + 4096 + sA[ks_]); \
        b0[ks_]     = *(const s16x8*)(BB +        sA[ks_]); } \
    if (SB) STAGE_B(OP, (T) + 1, 0); \
    BAR(); \
    __builtin_amdgcn_s_setprio(1); \
    _Pragma("unroll") \
    for (int ks_ = 0; ks_ < 4; ++ks_) { \
        MFMA32(acc00, a01[0][ks_], b0[ks_]); \
        MFMA32(acc10, a01[1][ks_], b0[ks_]); } \
    __builtin_amdgcn_s_setprio(0); \
    BAR(); \
    /* ---- phase 2: frags (m2,m3) x n0 ---- */ \
    _Pragma("unroll") \
    for (int ks_ = 0; ks_ < 4; ++ks_) { \
        a23[0][ks_] = *(const s16x8*)(AB +  8192 + sA[ks_]); \
        a23[1][ks_] = *(const s16x8*)(AB + 12288 + sA[ks_]); } \
    if (SB) STAGE_B(OP, (T) + 1, 1); \
    BAR(); \
    __builtin_amdgcn_s_setprio(1); \
    _Pragma("unroll") \
    for (int ks_ = 0; ks_ < 4; ++ks_) { \
        MFMA32(acc20, a23[0][ks_], b0[ks_]); \
        MFMA32(acc30, a23[1][ks_], b0[ks_]); } \
    __builtin_amdgcn_s_setprio(0); \
    BAR(); \
    /* ---- phase 3: frags (m0,m1) x n1 ---- */ \
    _Pragma("unroll") \
    for (int ks_ = 0; ks_ < 4; ++ks_) \
        b1[ks_] = *(const s16x8*)(BB + 4096 + sA[ks_]); \
    if (SA) STAGE_A(1 - (OP), (T) + 2, 0); \
    BAR(); \
    __builtin_amdgcn_s_setprio(1); \
    _Pragma("unroll") \
    for (int ks_ = 0; ks_ < 4; ++ks_) { \
        MFMA32(acc01, a01[0][ks_], b1[ks_]); \
        MFMA32(acc11, a01[1][ks_], b1[ks_]); } \
    __builtin_amdgcn_s_setprio(0); \
    BAR(); \
    /* ---- phase 4: frags (m2,m3) x n1 ---- */ \
    if (SA) STAGE_A(1 - (OP), (T) + 2, 1); \
    BAR(); \
    __builtin_amdgcn_s_setprio(1); \
    _Pragma("unroll") \
    for (int ks_ = 0; ks_ < 4; ++ks_) { \
        MFMA32(acc21, a23[0][ks_], b1[ks_]); \
        MFMA32(acc31, a23[1][ks_], b1[ks_]); } \
    __builtin_amdgcn_s_setprio(0); \
    /* tile boundary: counted drain (t+1 landed, t+2.A stays in flight) */ \
    if (VN) { asm volatile("s_waitcnt vmcnt(4)" ::: "memory"); } \
    else    { asm volatile("s_waitcnt vmcnt(0)" ::: "memory"); } \
    BAR(); \
} while (0)

    // prologue: tile0 fully + tile1.A; wait tile0 landed (4 newest = t1.A)
    STAGE_A(0, 0, 0); STAGE_A(0, 0, 1);
    STAGE_B(0, 0, 0); STAGE_B(0, 0, 1);
    STAGE_A(1, 1, 0); STAGE_A(1, 1, 1);
    asm volatile("s_waitcnt vmcnt(4)" ::: "memory");
    BAR();

    // main loop: tiles 0..61 (K/64 = 64 tiles total)
    // TILE(read-A-base, read-B-base, other-buf-index, tile, stageB, stageA, counted)
    #pragma unroll 1
    for (int t = 0; t < 62; t += 2) {
        TILE(aB0, bB0, 1, t,     1, 1, 1);
        TILE(aB1, bB1, 0, t + 1, 1, 1, 1);
    }
    // tile 62: stage 63.B only, full drain at boundary; tile 63: no staging
    TILE(aB0, bB0, 1, 62, 1, 0, 0);
    TILE(aB1, bB1, 0, 63, 0, 0, 0);

#undef TILE
#undef MFMA32
#undef BAR
#undef STAGE_A
#undef STAGE_B

    // epilogue: 32x32 C/D layout (m74/m101): col = lane&31,
    // row = (reg&3) + 8*(reg>>2) + 4*(lane>>5)
    float bv[2];
    #pragma unroll
    for (int nf = 0; nf < 2; ++nf)
        bv[nf] = bias[colBase + wc * 64 + nf * 32 + l31];

#define STORE(ACC, MF, NF) do { \
    _Pragma("unroll") \
    for (int rg = 0; rg < 4; ++rg) { \
        const int rowG = rowBase + wr * 128 + (MF) * 32 + 4 * hi + 8 * rg; \
        float* cp = C + (size_t)rowG * N + colBase + wc * 64 + (NF) * 32 + l31; \
        _Pragma("unroll") \
        for (int j = 0; j < 4; ++j) \
            cp[(size_t)j * N] = ACC[rg * 4 + j] + bv[NF]; \
    } \
} while (0)

    STORE(acc00, 0, 0); STORE(acc10, 1, 0); STORE(acc20, 2, 0); STORE(acc30, 3, 0);
    STORE(acc01, 0, 1); STORE(acc11, 1, 1); STORE(acc21, 2, 1); STORE(acc31, 3, 1);
#undef STORE
}

extern "C" void kernel_launch(void* const* d_in, const int* in_sizes, int n_in,
                              void* d_out, int out_size, void* d_ws, size_t ws_size,
                              hipStream_t stream) {
    const float* x     = (const float*)d_in[0];
    const float* W     = (const float*)d_in[1];
    const float* b     = (const float*)d_in[2];
    const float* dvals = (const float*)d_in[3];
    const int*   drows = (const int*)d_in[4];
    const int*   dcols = (const int*)d_in[5];
    float* out = (float*)d_out;

    char* ws = (char*)d_ws;
    float*          delta = (float*)ws;                                        // 64 MiB
    unsigned short* Wb    = (unsigned short*)(ws + (size_t)64 * 1024 * 1024);  // 32 MiB
    unsigned short* xb    = (unsigned short*)(ws + (size_t)96 * 1024 * 1024);  // 64 MiB

    int n4 = DOUT * DIN / 4;   // 4194304
    zero_kernel<<<n4 / 256, 256, 0, stream>>>(delta, n4);
    scatter_kernel<<<(NNZ_ + 255) / 256, 256, 0, stream>>>(dvals, drows, dcols, delta, NNZ_);
    int n8w = DOUT * DIN / 8;  // 2097152
    fuse_w_kernel<<<n8w / 256, 256, 0, stream>>>(W, delta, Wb, n8w);
    int n8x = M_ * DIN / 8;    // 4194304
    cvt_x_kernel<<<n8x / 256, 256, 0, stream>>>(x, xb, n8x);

    static bool attr_done = false;
    if (!attr_done) {
        (void)hipFuncSetAttribute(reinterpret_cast<const void*>(gemm_kernel),
                                  hipFuncAttributeMaxDynamicSharedMemorySize, 131072);
        attr_done = true;
    }
    // grid: 512 wgs (16 N-blocks x 32 M-blocks), 512 threads, 128 KiB LDS
    gemm_kernel<<<dim3(512), dim3(512), 131072, stream>>>(xb, Wb, b, out);
}

// Round 3
// 275.607 us; speedup vs baseline: 1.8511x; 1.8511x over previous
//
#include <hip/hip_runtime.h>
#include <hip/hip_bf16.h>
#include <stdint.h>

#define B_    4
#define S_    2048
#define DIN   4096
#define DOUT  4096
#define NNZ_  167772
#define M_    (B_*S_)   // 8192

typedef __attribute__((ext_vector_type(4))) float f32x4;
typedef __attribute__((ext_vector_type(8))) short s16x8;
typedef __attribute__((ext_vector_type(8))) unsigned short u16x8;

__device__ __forceinline__ unsigned short f2bf(float f) {
    unsigned int u = __float_as_uint(f);
    u += 0x7FFFu + ((u >> 16) & 1u);   // RNE; inputs finite, no NaN handling needed
    return (unsigned short)(u >> 16);
}

__device__ __forceinline__ float bf2f(unsigned short h) {
    return __uint_as_float(((unsigned int)h) << 16);
}

__device__ __forceinline__ void gload16(const void* g, void* l) {
    __builtin_amdgcn_global_load_lds(
        (const __attribute__((address_space(1))) unsigned int*)g,
        (__attribute__((address_space(3))) unsigned int*)l,
        16, 0, 0);
}

// ---- prep kernels ----
// Round 3: dense fp32 delta eliminated. One merged conversion kernel
// (W->Wb bf16, x->xb bf16), then a sparse bf16 CAS-scatter of the 167K
// corrections directly into Wb. Saves ~128 MB of prep traffic
// (64 MB zero-write + 64 MB delta re-read) and two launch gaps.

__global__ void cvt_both_kernel(const float* __restrict__ W,
                                const float* __restrict__ x,
                                unsigned short* __restrict__ Wb,
                                unsigned short* __restrict__ xb,
                                int n8w, int n8x) {
    int i = blockIdx.x * blockDim.x + threadIdx.x;
    const float* src;
    unsigned short* dst;
    int j;
    if (i < n8w) { src = W; dst = Wb; j = i; }
    else         { src = x; dst = xb; j = i - n8w; if (j >= n8x) return; }
    const f32x4* s4 = reinterpret_cast<const f32x4*>(src);
    f32x4 a0 = s4[2*j], a1 = s4[2*j+1];
    u16x8 o;
    o[0]=f2bf(a0[0]); o[1]=f2bf(a0[1]); o[2]=f2bf(a0[2]); o[3]=f2bf(a0[3]);
    o[4]=f2bf(a1[0]); o[5]=f2bf(a1[1]); o[6]=f2bf(a1[2]); o[7]=f2bf(a1[3]);
    reinterpret_cast<u16x8*>(dst)[j] = o;
}

__global__ void scatter_bf16_kernel(const float* __restrict__ vals,
                                    const int* __restrict__ rows,
                                    const int* __restrict__ cols,
                                    unsigned short* __restrict__ Wb, int nnz) {
    int i = blockIdx.x * blockDim.x + threadIdx.x;
    if (i >= nnz) return;
    size_t cell = (size_t)rows[i] * DIN + cols[i];
    unsigned int* word = reinterpret_cast<unsigned int*>(Wb) + (cell >> 1);
    const bool hiHalf = (cell & 1) != 0;
    const float v = vals[i];
    unsigned int old = *word, assumed;
    do {
        assumed = old;
        unsigned short h = hiHalf ? (unsigned short)(assumed >> 16)
                                  : (unsigned short)(assumed & 0xFFFFu);
        unsigned short nh = f2bf(bf2f(h) + v);
        unsigned int nw = hiHalf ? ((assumed & 0x0000FFFFu) | ((unsigned int)nh << 16))
                                 : ((assumed & 0xFFFF0000u) | (unsigned int)nh);
        old = atomicCAS(word, assumed, nw);
    } while (old != assumed);
}

// ---- GEMM: C[m][o] = sum_k xb[m][k] * Wb[o][k] + bias[o] ----
// Round-1 kernel verbatim (verified 236 us, MfmaUtil 52, bank conflicts 0).
// 256x256 tile, BK=64, 8 waves (2Mx4N), 512 threads, 128 KiB dynamic LDS
// (double-buffered A+B K-tiles). 8-phase schedule (4 phases per K-tile,
// 2 tiles per unrolled iteration) with counted vmcnt(4) at tile
// boundaries, XOR-swizzled LDS (slot ^= row&7, pre-swizzled global
// source so global_load_lds dest stays linear), setprio around MFMA
// clusters, bijective XCD block swizzle.
//
// Staging schedule (race-free by construction):
//   during tile t (reads buf[p=t&1]):
//     ph1: stage (t+1).B.h0 -> buf[1-p]   (buffer not read this tile)
//     ph2: stage (t+1).B.h1 -> buf[1-p]
//     ph3: stage (t+2).A.h0 -> buf[p]     (A-region reads consumed by ph2's
//     ph4: stage (t+2).A.h1 -> buf[p]      MFMA before ph2's 2nd barrier)
//   boundary: s_waitcnt vmcnt(4)  -> (t+1) fully landed, (t+2).A in flight

__global__ __launch_bounds__(512, 2) void gemm_kernel(
    const unsigned short* __restrict__ A,   // xb [M][K] bf16 bits
    const unsigned short* __restrict__ Bw,  // Wb [N][K] bf16 bits
    const float* __restrict__ bias,
    float* __restrict__ C)                  // [M][N] fp32
{
    constexpr int K  = DIN;    // 4096
    constexpr int N  = DOUT;   // 4096
    constexpr int KB = K * 2;  // 8192 bytes per row
    extern __shared__ char smem[];   // [2 bufs][A 32K | B 32K] = 128 KiB

    const int tid  = threadIdx.x;
    const int wave = tid >> 6;
    const int lane = tid & 63;
    const int wr = wave >> 2;          // 0..1  (M waves)
    const int wc = wave & 3;           // 0..3  (N waves)
    const int l16 = lane & 15;
    const int kq  = lane >> 4;         // 0..3
    const int s7  = l16 & 7;

    // XCD-aware bijective swizzle: 512 wgs, 8 XCDs -> 64 contiguous wgs/XCD.
    const int wg  = blockIdx.x;
    const int swz = (wg & 7) * 64 + (wg >> 3);
    const int bx  = swz & 15;          // N block 0..15
    const int by  = swz >> 4;          // M block 0..31
    const int rowBase = by * 256;
    const int colBase = bx * 256;

    // staging: per-thread global source, pre-swizzled (slot ^= row&7).
    // LDS dest stays linear: base + instr*8192 + wave*1024 (+ lane*16 impl.)
    const int r0    = tid >> 3;                   // row within 64-row chunk
    const int gslot = (tid & 7) ^ (r0 & 7);
    const char* gA = (const char*)A  + (size_t)(rowBase + r0) * KB + gslot * 16;
    const char* gB = (const char*)Bw + (size_t)(colBase + r0) * KB + gslot * 16;
    const int wvoff = wave * 1024;

    // LDS read pointers: row*128B + ((ks*4+kq)^s7)*16B, per buffer.
    const unsigned q0 = (unsigned)(kq ^ s7);        // ks=0 slot
    const unsigned q1 = (unsigned)((4 + kq) ^ s7);  // ks=1 slot
    const unsigned aBase = (unsigned)((wr * 128 + l16) * 128);
    const unsigned bBase = (unsigned)((wc * 64  + l16) * 128);
    const unsigned short* aPtr[2][2];
    const unsigned short* bPtr[2][2];
    #pragma unroll
    for (int p_ = 0; p_ < 2; ++p_) {
        aPtr[p_][0] = (const unsigned short*)(smem + p_ * 65536 + aBase + q0 * 16);
        aPtr[p_][1] = (const unsigned short*)(smem + p_ * 65536 + aBase + q1 * 16);
        bPtr[p_][0] = (const unsigned short*)(smem + p_ * 65536 + 32768 + bBase + q0 * 16);
        bPtr[p_][1] = (const unsigned short*)(smem + p_ * 65536 + 32768 + bBase + q1 * 16);
    }

    f32x4 acc[8][4];
    #pragma unroll
    for (int i = 0; i < 8; ++i)
        #pragma unroll
        for (int j = 0; j < 4; ++j) acc[i][j] = f32x4{0.f, 0.f, 0.f, 0.f};

#define STAGE_A(P, T, H) do { \
    const char* g_ = gA + (size_t)(T) * 128 + (size_t)(H) * 1048576; \
    gload16(g_,          smem + (P) * 65536 + (H) * 16384 + wvoff); \
    gload16(g_ + 524288, smem + (P) * 65536 + (H) * 16384 + 8192 + wvoff); \
} while (0)

#define STAGE_B(P, T, H) do { \
    const char* g_ = gB + (size_t)(T) * 128 + (size_t)(H) * 1048576; \
    gload16(g_,          smem + (P) * 65536 + 32768 + (H) * 16384 + wvoff); \
    gload16(g_ + 524288, smem + (P) * 65536 + 32768 + (H) * 16384 + 8192 + wvoff); \
} while (0)

#define BAR() asm volatile("s_barrier" ::: "memory")

#define TILE(P, T, SB, SA, VN) do { \
    s16x8 af0[4][2], af1[4][2], bf0[2][2], bf1[2][2]; \
    /* ---- phase 1: quad(mh0, nh0) ---- */ \
    _Pragma("unroll") \
    for (int m_ = 0; m_ < 4; ++m_) { \
        af0[m_][0] = *(const s16x8*)(aPtr[P][0] + m_ * 1024); \
        af0[m_][1] = *(const s16x8*)(aPtr[P][1] + m_ * 1024); } \
    _Pragma("unroll") \
    for (int n_ = 0; n_ < 2; ++n_) { \
        bf0[n_][0] = *(const s16x8*)(bPtr[P][0] + n_ * 1024); \
        bf0[n_][1] = *(const s16x8*)(bPtr[P][1] + n_ * 1024); } \
    if (SB) STAGE_B(1 - (P), (T) + 1, 0); \
    BAR(); \
    __builtin_amdgcn_s_setprio(1); \
    _Pragma("unroll") \
    for (int m_ = 0; m_ < 4; ++m_) \
      _Pragma("unroll") \
      for (int n_ = 0; n_ < 2; ++n_) { \
        acc[m_][n_] = __builtin_amdgcn_mfma_f32_16x16x32_bf16(af0[m_][0], bf0[n_][0], acc[m_][n_], 0, 0, 0); \
        acc[m_][n_] = __builtin_amdgcn_mfma_f32_16x16x32_bf16(af0[m_][1], bf0[n_][1], acc[m_][n_], 0, 0, 0); } \
    __builtin_amdgcn_s_setprio(0); \
    BAR(); \
    /* ---- phase 2: quad(mh1, nh0) ---- */ \
    _Pragma("unroll") \
    for (int m_ = 0; m_ < 4; ++m_) { \
        af1[m_][0] = *(const s16x8*)(aPtr[P][0] + 4096 + m_ * 1024); \
        af1[m_][1] = *(const s16x8*)(aPtr[P][1] + 4096 + m_ * 1024); } \
    if (SB) STAGE_B(1 - (P), (T) + 1, 1); \
    BAR(); \
    __builtin_amdgcn_s_setprio(1); \
    _Pragma("unroll") \
    for (int m_ = 0; m_ < 4; ++m_) \
      _Pragma("unroll") \
      for (int n_ = 0; n_ < 2; ++n_) { \
        acc[4 + m_][n_] = __builtin_amdgcn_mfma_f32_16x16x32_bf16(af1[m_][0], bf0[n_][0], acc[4 + m_][n_], 0, 0, 0); \
        acc[4 + m_][n_] = __builtin_amdgcn_mfma_f32_16x16x32_bf16(af1[m_][1], bf0[n_][1], acc[4 + m_][n_], 0, 0, 0); } \
    __builtin_amdgcn_s_setprio(0); \
    BAR(); \
    /* ---- phase 3: quad(mh0, nh1) ---- */ \
    _Pragma("unroll") \
    for (int n_ = 0; n_ < 2; ++n_) { \
        bf1[n_][0] = *(const s16x8*)(bPtr[P][0] + 2048 + n_ * 1024); \
        bf1[n_][1] = *(const s16x8*)(bPtr[P][1] + 2048 + n_ * 1024); } \
    if (SA) STAGE_A(P, (T) + 2, 0); \
    BAR(); \
    __builtin_amdgcn_s_setprio(1); \
    _Pragma("unroll") \
    for (int m_ = 0; m_ < 4; ++m_) \
      _Pragma("unroll") \
      for (int n_ = 0; n_ < 2; ++n_) { \
        acc[m_][2 + n_] = __builtin_amdgcn_mfma_f32_16x16x32_bf16(af0[m_][0], bf1[n_][0], acc[m_][2 + n_], 0, 0, 0); \
        acc[m_][2 + n_] = __builtin_amdgcn_mfma_f32_16x16x32_bf16(af0[m_][1], bf1[n_][1], acc[m_][2 + n_], 0, 0, 0); } \
    __builtin_amdgcn_s_setprio(0); \
    BAR(); \
    /* ---- phase 4: quad(mh1, nh1) ---- */ \
    if (SA) STAGE_A(P, (T) + 2, 1); \
    BAR(); \
    __builtin_amdgcn_s_setprio(1); \
    _Pragma("unroll") \
    for (int m_ = 0; m_ < 4; ++m_) \
      _Pragma("unroll") \
      for (int n_ = 0; n_ < 2; ++n_) { \
        acc[4 + m_][2 + n_] = __builtin_amdgcn_mfma_f32_16x16x32_bf16(af1[m_][0], bf1[n_][0], acc[4 + m_][2 + n_], 0, 0, 0); \
        acc[4 + m_][2 + n_] = __builtin_amdgcn_mfma_f32_16x16x32_bf16(af1[m_][1], bf1[n_][1], acc[4 + m_][2 + n_], 0, 0, 0); } \
    __builtin_amdgcn_s_setprio(0); \
    /* tile boundary: counted drain (next tile landed, t+2.A stays in flight) */ \
    if (VN) { asm volatile("s_waitcnt vmcnt(4)" ::: "memory"); } \
    else    { asm volatile("s_waitcnt vmcnt(0)" ::: "memory"); } \
    BAR(); \
} while (0)

    // prologue: tile0 fully + tile1.A; wait tile0 landed (4 newest = t1.A)
    STAGE_A(0, 0, 0); STAGE_A(0, 0, 1);
    STAGE_B(0, 0, 0); STAGE_B(0, 0, 1);
    STAGE_A(1, 1, 0); STAGE_A(1, 1, 1);
    asm volatile("s_waitcnt vmcnt(4)" ::: "memory");
    BAR();

    // main loop: tiles 0..61 (K/64 = 64 tiles total)
    #pragma unroll 1
    for (int t = 0; t < 62; t += 2) {
        TILE(0, t,     1, 1, 4);
        TILE(1, t + 1, 1, 1, 4);
    }
    // tile 62: stage 63.B only, full drain at boundary; tile 63: no staging
    TILE(0, 62, 1, 0, 0);
    TILE(1, 63, 0, 0, 0);

#undef TILE
#undef BAR
#undef STAGE_A
#undef STAGE_B

    // epilogue: C/D layout col = lane&15, row = (lane>>4)*4 + j
    float bv[4];
    #pragma unroll
    for (int nf = 0; nf < 4; ++nf)
        bv[nf] = bias[colBase + wc * 64 + nf * 16 + l16];

    #pragma unroll
    for (int mf = 0; mf < 8; ++mf) {
        const int rowG = rowBase + wr * 128 + mf * 16 + kq * 4;
        float* cp = C + (size_t)rowG * N + colBase + wc * 64 + l16;
        #pragma unroll
        for (int nf = 0; nf < 4; ++nf)
            #pragma unroll
            for (int j = 0; j < 4; ++j)
                cp[(size_t)j * N + nf * 16] = acc[mf][nf][j] + bv[nf];
    }
}

extern "C" void kernel_launch(void* const* d_in, const int* in_sizes, int n_in,
                              void* d_out, int out_size, void* d_ws, size_t ws_size,
                              hipStream_t stream) {
    const float* x     = (const float*)d_in[0];
    const float* W     = (const float*)d_in[1];
    const float* b     = (const float*)d_in[2];
    const float* dvals = (const float*)d_in[3];
    const int*   drows = (const int*)d_in[4];
    const int*   dcols = (const int*)d_in[5];
    float* out = (float*)d_out;

    char* ws = (char*)d_ws;
    unsigned short* Wb = (unsigned short*)ws;                                   // 32 MiB
    unsigned short* xb = (unsigned short*)(ws + (size_t)32 * 1024 * 1024);      // 64 MiB

    // prep: one merged conversion pass (W->Wb, x->xb), then sparse
    // bf16 CAS-scatter of the corrections into Wb.
    int n8w = DOUT * DIN / 8;  // 2097152
    int n8x = M_ * DIN / 8;    // 4194304
    int nblk = (n8w + n8x) / 256;  // 24576
    cvt_both_kernel<<<nblk, 256, 0, stream>>>(W, x, Wb, xb, n8w, n8x);
    scatter_bf16_kernel<<<(NNZ_ + 255) / 256, 256, 0, stream>>>(dvals, drows, dcols, Wb, NNZ_);

    static bool attr_done = false;
    if (!attr_done) {
        (void)hipFuncSetAttribute(reinterpret_cast<const void*>(gemm_kernel),
                                  hipFuncAttributeMaxDynamicSharedMemorySize, 131072);
        attr_done = true;
    }
    // grid: 512 wgs (16 N-blocks x 32 M-blocks), 512 threads, 128 KiB LDS
    gemm_kernel<<<dim3(512), dim3(512), 131072, stream>>>(xb, Wb, b, out);
}

// Round 4
// 267.012 us; speedup vs baseline: 1.9107x; 1.0322x over previous
//
#include <hip/hip_runtime.h>
#include <hip/hip_bf16.h>
#include <stdint.h>

#define B_    4
#define S_    2048
#define DIN   4096
#define DOUT  4096
#define NNZ_  167772
#define M_    (B_*S_)   // 8192

typedef __attribute__((ext_vector_type(4))) float f32x4;
typedef __attribute__((ext_vector_type(8))) short s16x8;
typedef __attribute__((ext_vector_type(8))) unsigned short u16x8;

__device__ __forceinline__ unsigned short f2bf(float f) {
    unsigned int u = __float_as_uint(f);
    u += 0x7FFFu + ((u >> 16) & 1u);   // RNE; inputs finite, no NaN handling needed
    return (unsigned short)(u >> 16);
}

__device__ __forceinline__ float bf2f(unsigned short h) {
    return __uint_as_float(((unsigned int)h) << 16);
}

__device__ __forceinline__ void gload16(const void* g, void* l) {
    __builtin_amdgcn_global_load_lds(
        (const __attribute__((address_space(1))) unsigned int*)g,
        (__attribute__((address_space(3))) unsigned int*)l,
        16, 0, 0);
}

// ---- prep kernels (round-3 verified: no dense delta; bf16 CAS scatter) ----

__global__ void cvt_both_kernel(const float* __restrict__ W,
                                const float* __restrict__ x,
                                unsigned short* __restrict__ Wb,
                                unsigned short* __restrict__ xb,
                                int n8w, int n8x) {
    int i = blockIdx.x * blockDim.x + threadIdx.x;
    const float* src;
    unsigned short* dst;
    int j;
    if (i < n8w) { src = W; dst = Wb; j = i; }
    else         { src = x; dst = xb; j = i - n8w; if (j >= n8x) return; }
    const f32x4* s4 = reinterpret_cast<const f32x4*>(src);
    f32x4 a0 = s4[2*j], a1 = s4[2*j+1];
    u16x8 o;
    o[0]=f2bf(a0[0]); o[1]=f2bf(a0[1]); o[2]=f2bf(a0[2]); o[3]=f2bf(a0[3]);
    o[4]=f2bf(a1[0]); o[5]=f2bf(a1[1]); o[6]=f2bf(a1[2]); o[7]=f2bf(a1[3]);
    reinterpret_cast<u16x8*>(dst)[j] = o;
}

__global__ void scatter_bf16_kernel(const float* __restrict__ vals,
                                    const int* __restrict__ rows,
                                    const int* __restrict__ cols,
                                    unsigned short* __restrict__ Wb, int nnz) {
    int i = blockIdx.x * blockDim.x + threadIdx.x;
    if (i >= nnz) return;
    size_t cell = (size_t)rows[i] * DIN + cols[i];
    unsigned int* word = reinterpret_cast<unsigned int*>(Wb) + (cell >> 1);
    const bool hiHalf = (cell & 1) != 0;
    const float v = vals[i];
    unsigned int old = *word, assumed;
    do {
        assumed = old;
        unsigned short h = hiHalf ? (unsigned short)(assumed >> 16)
                                  : (unsigned short)(assumed & 0xFFFFu);
        unsigned short nh = f2bf(bf2f(h) + v);
        unsigned int nw = hiHalf ? ((assumed & 0x0000FFFFu) | ((unsigned int)nh << 16))
                                 : ((assumed & 0xFFFF0000u) | (unsigned int)nh);
        old = atomicCAS(word, assumed, nw);
    } while (old != assumed);
}

// ---- GEMM: C[m][o] = sum_k xb[m][k] * Wb[o][k] + bias[o] ----
// Round 4: single-barrier phases with one-phase-lookahead ds_reads.
// 256x256 tile, BK=64, 8 waves (2Mx4N), 512 threads, 128 KiB dynamic LDS.
// Phase order per tile: S1 af0*bf0, S2 af0*bf1, S3 af1*bf1, S4 af1*bf0.
// Fragments are read ONE segment before their consuming MFMA so ds_read
// pipe time hides under MFMA pipe time. BOTH A and B staged 2 tiles
// ahead (t+2 -> the buffer currently being read, after its readers'
// lgkm + 1 barrier). All stages issue after the fence, so the per-tile
// fence is a plain vmcnt(0) covering exactly tile t+1's 8 loads (issued
// a full tile ago), with S3's barrier as the cross-wave fence.
//
// Per-tile schedule (reads buf p = t&1; 4 barriers/tile):
//   S1: BAR; MFMA af0*bf0            || read bf1(t)
//   S2: BAR; MFMA af0*bf1            || read af1(t);  vmcnt(0) fence
//   S3: BAR; MFMA af1*bf1            || read af0(t+1) [buf 1-p]; stage B(t+2)->buf p
//   S4: BAR; MFMA af1*bf0            || read bf0(t+1) [buf 1-p]; stage A(t+2)->buf p
// Hazard ledger (stage to R >= readers' lgkm + 1 barrier):
//   B(t+2).h0/h1 -> buf p.B: readers bf0(t) [read prev S4, lgkm S1],
//     bf1(t) [read S1, lgkm S2] -> safe from S3.  A(t+2).h0/h1 -> buf p.A:
//     readers af0(t) [prev S3, lgkm S1], af1(t) [S2, lgkm S3] -> safe S4.

__global__ __launch_bounds__(512, 2) void gemm_kernel(
    const unsigned short* __restrict__ A,   // xb [M][K] bf16 bits
    const unsigned short* __restrict__ Bw,  // Wb [N][K] bf16 bits
    const float* __restrict__ bias,
    float* __restrict__ C)                  // [M][N] fp32
{
    constexpr int K  = DIN;    // 4096
    constexpr int N  = DOUT;   // 4096
    constexpr int KB = K * 2;  // 8192 bytes per row
    extern __shared__ char smem[];   // [2 bufs][A 32K | B 32K] = 128 KiB

    const int tid  = threadIdx.x;
    const int wave = tid >> 6;
    const int lane = tid & 63;
    const int wr = wave >> 2;          // 0..1  (M waves)
    const int wc = wave & 3;           // 0..3  (N waves)
    const int l16 = lane & 15;
    const int kq  = lane >> 4;         // 0..3
    const int s7  = l16 & 7;

    // XCD-aware bijective swizzle: 512 wgs, 8 XCDs -> 64 contiguous wgs/XCD.
    const int wg  = blockIdx.x;
    const int swz = (wg & 7) * 64 + (wg >> 3);
    const int bx  = swz & 15;          // N block 0..15
    const int by  = swz >> 4;          // M block 0..31
    const int rowBase = by * 256;
    const int colBase = bx * 256;

    // staging: per-thread global source, pre-swizzled (slot ^= row&7).
    // LDS dest stays linear: base + instr*8192 + wave*1024 (+ lane*16 impl.)
    const int r0    = tid >> 3;                   // row within 64-row chunk
    const int gslot = (tid & 7) ^ (r0 & 7);
    const char* gA = (const char*)A  + (size_t)(rowBase + r0) * KB + gslot * 16;
    const char* gB = (const char*)Bw + (size_t)(colBase + r0) * KB + gslot * 16;
    const int wvoff = wave * 1024;

    // LDS read pointers: row*128B + ((ks*4+kq)^s7)*16B, per buffer.
    const unsigned q0 = (unsigned)(kq ^ s7);        // ks=0 slot
    const unsigned q1 = (unsigned)((4 + kq) ^ s7);  // ks=1 slot
    const unsigned aBase = (unsigned)((wr * 128 + l16) * 128);
    const unsigned bBase = (unsigned)((wc * 64  + l16) * 128);
    const unsigned short* aPtr[2][2];
    const unsigned short* bPtr[2][2];
    #pragma unroll
    for (int p_ = 0; p_ < 2; ++p_) {
        aPtr[p_][0] = (const unsigned short*)(smem + p_ * 65536 + aBase + q0 * 16);
        aPtr[p_][1] = (const unsigned short*)(smem + p_ * 65536 + aBase + q1 * 16);
        bPtr[p_][0] = (const unsigned short*)(smem + p_ * 65536 + 32768 + bBase + q0 * 16);
        bPtr[p_][1] = (const unsigned short*)(smem + p_ * 65536 + 32768 + bBase + q1 * 16);
    }

    f32x4 acc[8][4];
    #pragma unroll
    for (int i = 0; i < 8; ++i)
        #pragma unroll
        for (int j = 0; j < 4; ++j) acc[i][j] = f32x4{0.f, 0.f, 0.f, 0.f};

    // persistent fragment registers (live across tiles)
    s16x8 af0[4][2], af1[4][2], bf0[2][2], bf1[2][2];

#define STAGE_A(P, T, H) do { \
    const char* g_ = gA + (size_t)(T) * 128 + (size_t)(H) * 1048576; \
    gload16(g_,          smem + (P) * 65536 + (H) * 16384 + wvoff); \
    gload16(g_ + 524288, smem + (P) * 65536 + (H) * 16384 + 8192 + wvoff); \
} while (0)

#define STAGE_B(P, T, H) do { \
    const char* g_ = gB + (size_t)(T) * 128 + (size_t)(H) * 1048576; \
    gload16(g_,          smem + (P) * 65536 + 32768 + (H) * 16384 + wvoff); \
    gload16(g_ + 524288, smem + (P) * 65536 + 32768 + (H) * 16384 + 8192 + wvoff); \
} while (0)

#define BAR() asm volatile("s_barrier" ::: "memory")

#define MFMA16(D, Af, Bf) D = __builtin_amdgcn_mfma_f32_16x16x32_bf16(Af, Bf, D, 0, 0, 0)

// TILE(P = buffer parity, T = tile index, SS = stage t+2, FN = fence+prefetch t+1)
#define TILE(P, T, SS, FN) do { \
    /* ---- S1: af0*bf0 -> acc[0..3][0..1]; read bf1(t) ---- */ \
    BAR(); \
    __builtin_amdgcn_s_setprio(1); \
    _Pragma("unroll") \
    for (int m_ = 0; m_ < 4; ++m_) \
      _Pragma("unroll") \
      for (int n_ = 0; n_ < 2; ++n_) { \
        MFMA16(acc[m_][n_], af0[m_][0], bf0[n_][0]); \
        MFMA16(acc[m_][n_], af0[m_][1], bf0[n_][1]); } \
    __builtin_amdgcn_s_setprio(0); \
    _Pragma("unroll") \
    for (int n_ = 0; n_ < 2; ++n_) { \
        bf1[n_][0] = *(const s16x8*)(bPtr[P][0] + 2048 + n_ * 1024); \
        bf1[n_][1] = *(const s16x8*)(bPtr[P][1] + 2048 + n_ * 1024); } \
    /* ---- S2: af0*bf1 -> acc[0..3][2..3]; read af1(t); fence ---- */ \
    BAR(); \
    __builtin_amdgcn_s_setprio(1); \
    _Pragma("unroll") \
    for (int m_ = 0; m_ < 4; ++m_) \
      _Pragma("unroll") \
      for (int n_ = 0; n_ < 2; ++n_) { \
        MFMA16(acc[m_][2 + n_], af0[m_][0], bf1[n_][0]); \
        MFMA16(acc[m_][2 + n_], af0[m_][1], bf1[n_][1]); } \
    __builtin_amdgcn_s_setprio(0); \
    _Pragma("unroll") \
    for (int m_ = 0; m_ < 4; ++m_) { \
        af1[m_][0] = *(const s16x8*)(aPtr[P][0] + 4096 + m_ * 1024); \
        af1[m_][1] = *(const s16x8*)(aPtr[P][1] + 4096 + m_ * 1024); } \
    if (FN) { asm volatile("s_waitcnt vmcnt(0)" ::: "memory"); } \
    /* ---- S3: af1*bf1 -> acc[4..7][2..3]; read af0(t+1); stage B(t+2) ---- */ \
    BAR(); \
    __builtin_amdgcn_s_setprio(1); \
    _Pragma("unroll") \
    for (int m_ = 0; m_ < 4; ++m_) \
      _Pragma("unroll") \
      for (int n_ = 0; n_ < 2; ++n_) { \
        MFMA16(acc[4 + m_][2 + n_], af1[m_][0], bf1[n_][0]); \
        MFMA16(acc[4 + m_][2 + n_], af1[m_][1], bf1[n_][1]); } \
    __builtin_amdgcn_s_setprio(0); \
    if (FN) { \
      _Pragma("unroll") \
      for (int m_ = 0; m_ < 4; ++m_) { \
        af0[m_][0] = *(const s16x8*)(aPtr[1 - (P)][0] + m_ * 1024); \
        af0[m_][1] = *(const s16x8*)(aPtr[1 - (P)][1] + m_ * 1024); } } \
    if (SS) { STAGE_B(P, (T) + 2, 0); STAGE_B(P, (T) + 2, 1); } \
    /* ---- S4: af1*bf0 -> acc[4..7][0..1]; read bf0(t+1); stage A(t+2) ---- */ \
    BAR(); \
    __builtin_amdgcn_s_setprio(1); \
    _Pragma("unroll") \
    for (int m_ = 0; m_ < 4; ++m_) \
      _Pragma("unroll") \
      for (int n_ = 0; n_ < 2; ++n_) { \
        MFMA16(acc[4 + m_][n_], af1[m_][0], bf0[n_][0]); \
        MFMA16(acc[4 + m_][n_], af1[m_][1], bf0[n_][1]); } \
    __builtin_amdgcn_s_setprio(0); \
    if (FN) { \
      _Pragma("unroll") \
      for (int n_ = 0; n_ < 2; ++n_) { \
        bf0[n_][0] = *(const s16x8*)(bPtr[1 - (P)][0] + n_ * 1024); \
        bf0[n_][1] = *(const s16x8*)(bPtr[1 - (P)][1] + n_ * 1024); } } \
    if (SS) { STAGE_A(P, (T) + 2, 0); STAGE_A(P, (T) + 2, 1); } \
} while (0)

    // prologue: stage tile0 (buf0) then tile1 (buf1, B first to match
    // steady-state issue order); wait tile0 (oldest 8); pre-read af0/bf0.
    STAGE_A(0, 0, 0); STAGE_A(0, 0, 1);
    STAGE_B(0, 0, 0); STAGE_B(0, 0, 1);
    STAGE_B(1, 1, 0); STAGE_B(1, 1, 1);
    STAGE_A(1, 1, 0); STAGE_A(1, 1, 1);
    asm volatile("s_waitcnt vmcnt(8)" ::: "memory");
    BAR();
    #pragma unroll
    for (int m_ = 0; m_ < 4; ++m_) {
        af0[m_][0] = *(const s16x8*)(aPtr[0][0] + m_ * 1024);
        af0[m_][1] = *(const s16x8*)(aPtr[0][1] + m_ * 1024);
    }
    #pragma unroll
    for (int n_ = 0; n_ < 2; ++n_) {
        bf0[n_][0] = *(const s16x8*)(bPtr[0][0] + n_ * 1024);
        bf0[n_][1] = *(const s16x8*)(bPtr[0][1] + n_ * 1024);
    }

    // main loop: tiles 0..61 stage t+2; t=62 fence+prefetch only; t=63 drains.
    #pragma unroll 1
    for (int t = 0; t < 62; t += 2) {
        TILE(0, t,     1, 1);
        TILE(1, t + 1, 1, 1);
    }
    TILE(0, 62, 0, 1);
    TILE(1, 63, 0, 0);

#undef TILE
#undef MFMA16
#undef BAR
#undef STAGE_A
#undef STAGE_B

    // epilogue: C/D layout col = lane&15, row = (lane>>4)*4 + j
    float bv[4];
    #pragma unroll
    for (int nf = 0; nf < 4; ++nf)
        bv[nf] = bias[colBase + wc * 64 + nf * 16 + l16];

    #pragma unroll
    for (int mf = 0; mf < 8; ++mf) {
        const int rowG = rowBase + wr * 128 + mf * 16 + kq * 4;
        float* cp = C + (size_t)rowG * N + colBase + wc * 64 + l16;
        #pragma unroll
        for (int nf = 0; nf < 4; ++nf)
            #pragma unroll
            for (int j = 0; j < 4; ++j)
                cp[(size_t)j * N + nf * 16] = acc[mf][nf][j] + bv[nf];
    }
}

extern "C" void kernel_launch(void* const* d_in, const int* in_sizes, int n_in,
                              void* d_out, int out_size, void* d_ws, size_t ws_size,
                              hipStream_t stream) {
    const float* x     = (const float*)d_in[0];
    const float* W     = (const float*)d_in[1];
    const float* b     = (const float*)d_in[2];
    const float* dvals = (const float*)d_in[3];
    const int*   drows = (const int*)d_in[4];
    const int*   dcols = (const int*)d_in[5];
    float* out = (float*)d_out;

    char* ws = (char*)d_ws;
    unsigned short* Wb = (unsigned short*)ws;                                   // 32 MiB
    unsigned short* xb = (unsigned short*)(ws + (size_t)32 * 1024 * 1024);      // 64 MiB

    // prep: one merged conversion pass (W->Wb, x->xb), then sparse
    // bf16 CAS-scatter of the corrections into Wb.
    int n8w = DOUT * DIN / 8;  // 2097152
    int n8x = M_ * DIN / 8;    // 4194304
    int nblk = (n8w + n8x) / 256;  // 24576
    cvt_both_kernel<<<nblk, 256, 0, stream>>>(W, x, Wb, xb, n8w, n8x);
    scatter_bf16_kernel<<<(NNZ_ + 255) / 256, 256, 0, stream>>>(dvals, drows, dcols, Wb, NNZ_);

    static bool attr_done = false;
    if (!attr_done) {
        (void)hipFuncSetAttribute(reinterpret_cast<const void*>(gemm_kernel),
                                  hipFuncAttributeMaxDynamicSharedMemorySize, 131072);
        attr_done = true;
    }
    // grid: 512 wgs (16 N-blocks x 32 M-blocks), 512 threads, 128 KiB LDS
    gemm_kernel<<<dim3(512), dim3(512), 131072, stream>>>(xb, Wb, b, out);
}